// Round 8
// baseline (1606.004 us; speedup 1.0000x reference)
//
#include <hip/hip_runtime.h>

#define BB 32
#define TT 2048
#define DD 256
#define HH 256
#define AA 128
#define CC 4367
#define NSTEPS 22

typedef unsigned short ushortT;
typedef unsigned int uintT;
using frag8 = __attribute__((ext_vector_type(8))) short;
using f32x4 = __attribute__((ext_vector_type(4))) float;

__device__ __forceinline__ float tanh_fast(float u) {
  float e = __expf(2.0f * u);
  return 1.0f - 2.0f / (e + 1.0f);
}
__device__ __forceinline__ float sigmoid_fast(float u) {
  return 1.0f / (1.0f + __expf(-u));
}
__device__ __forceinline__ ushortT f2bf(float f) {
  unsigned int u = __float_as_uint(f);
  unsigned int r = (u + 0x7FFFu + ((u >> 16) & 1u)) >> 16;
  return (ushortT)r;
}
__device__ __forceinline__ float bflo(uintT u) { return __uint_as_float(u << 16); }
__device__ __forceinline__ float bfhi(uintT u) { return __uint_as_float(u & 0xffff0000u); }

__device__ __forceinline__ void wait_ge(int* p, int tgt) {
  while (__hip_atomic_load(p, __ATOMIC_RELAXED, __HIP_MEMORY_SCOPE_AGENT) < tgt)
    __builtin_amdgcn_s_sleep(2);
}
__device__ __forceinline__ float aload(const float* p) {
  return __hip_atomic_load(p, __ATOMIC_RELAXED, __HIP_MEMORY_SCOPE_AGENT);
}
__device__ __forceinline__ void dot8(const float* cp, uint4 w, float& acc) {
  acc = fmaf(cp[0], bflo(w.x), acc); acc = fmaf(cp[1], bfhi(w.x), acc);
  acc = fmaf(cp[2], bflo(w.y), acc); acc = fmaf(cp[3], bfhi(w.y), acc);
  acc = fmaf(cp[4], bflo(w.z), acc); acc = fmaf(cp[5], bfhi(w.z), acc);
  acc = fmaf(cp[6], bflo(w.w), acc); acc = fmaf(cp[7], bfhi(w.w), acc);
}

// ---------- prep: bf16 conversions + WxT transpose ----------
__global__ __launch_bounds__(256) void conv_kernel(
    const float* __restrict__ Wx, const float* __restrict__ W_cls,
    const float* __restrict__ W_ih, const float* __restrict__ W_hh,
    const float* __restrict__ Wh,
    ushortT* __restrict__ Wcls_bf, ushortT* __restrict__ Wih_bf,
    ushortT* __restrict__ Whh_bf, ushortT* __restrict__ Wh_bf,
    ushortT* __restrict__ WxT_bf) {
  int blk = blockIdx.x;
  const int tid = threadIdx.x;
  if (blk < 384) {
    const float* src; ushortT* dst; int base, srcn;
    if (blk < 280)      { src = W_cls; dst = Wcls_bf; base = blk * 4096;        srcn = CC * 256; }
    else if (blk < 328) { src = W_ih;  dst = Wih_bf;  base = (blk - 280) * 4096; srcn = 768 * 256; }
    else if (blk < 376) { src = W_hh;  dst = Whh_bf;  base = (blk - 328) * 4096; srcn = 768 * 256; }
    else                { src = Wh;    dst = Wh_bf;   base = (blk - 376) * 4096; srcn = 256 * 128; }
#pragma unroll
    for (int i = 0; i < 16; ++i) {
      int idx = base + i * 256 + tid;
      dst[idx] = (idx < srcn) ? f2bf(src[idx]) : (ushortT)0;
    }
  } else {  // Wx [256][128] -> WxT_bf [128][256]
    blk -= 384;  // 0..31
    __shared__ float tile[32][33];
    const int li = tid >> 5, lj = tid & 31;
    int i0 = (blk >> 2) * 32, j0 = (blk & 3) * 32;
#pragma unroll
    for (int k = 0; k < 4; ++k)
      tile[li + k * 8][lj] = Wx[(size_t)(i0 + li + k * 8) * 128 + j0 + lj];
    __syncthreads();
#pragma unroll
    for (int k = 0; k < 4; ++k) {
      int j = j0 + li + k * 8;
      WxT_bf[(size_t)j * 256 + i0 + lj] = f2bf(tile[lj][li + k * 8]);
    }
  }
}

// ---------- xW via MFMA bf16 (validated): emits x_bf and xWT ----------
__global__ __launch_bounds__(256) void xw_mfma(
    const float* __restrict__ x, const ushortT* __restrict__ WxT_bf,
    ushortT* __restrict__ x_bf, ushortT* __restrict__ xWT) {
  __shared__ ushortT lds[2 * 128 * 72];
#define SX(r, c) lds[(r) * 72 + (c)]
#define SW(r, c) lds[128 * 72 + (r) * 72 + (c)]
#define ST(a, m) lds[(a) * 136 + (m)]
  const int tid = threadIdx.x;
  const int lane = tid & 63, w = tid >> 6;
  const int l15 = lane & 15, quad = lane >> 4;
  const int r0 = blockIdx.x * 128;
  const int bb = blockIdx.x >> 4, t0 = (blockIdx.x & 15) * 128;
  const int row = tid >> 1, half = tid & 1;

  f32x4 acc[2][8];
#pragma unroll
  for (int mt = 0; mt < 2; ++mt)
#pragma unroll
    for (int nt = 0; nt < 8; ++nt) acc[mt][nt] = (f32x4){0.f, 0.f, 0.f, 0.f};

  for (int kk0 = 0; kk0 < 256; kk0 += 64) {
    {
      const float4* xp = (const float4*)(x + (size_t)(r0 + row) * DD + kk0 + half * 32);
      uint4 pk[4];
#pragma unroll
      for (int i = 0; i < 4; ++i) {
        float4 f0 = xp[2 * i], f1 = xp[2 * i + 1];
        pk[i].x = (uintT)f2bf(f0.x) | ((uintT)f2bf(f0.y) << 16);
        pk[i].y = (uintT)f2bf(f0.z) | ((uintT)f2bf(f0.w) << 16);
        pk[i].z = (uintT)f2bf(f1.x) | ((uintT)f2bf(f1.y) << 16);
        pk[i].w = (uintT)f2bf(f1.z) | ((uintT)f2bf(f1.w) << 16);
      }
      uint4* sxp = (uint4*)&SX(row, half * 32);
      uint4* gxp = (uint4*)(x_bf + (size_t)(r0 + row) * DD + kk0 + half * 32);
#pragma unroll
      for (int i = 0; i < 4; ++i) { sxp[i] = pk[i]; gxp[i] = pk[i]; }
    }
    {
      const uint4* wp = (const uint4*)(WxT_bf + (size_t)row * DD + kk0 + half * 32);
      uint4* swp = (uint4*)&SW(row, half * 32);
#pragma unroll
      for (int i = 0; i < 4; ++i) swp[i] = wp[i];
    }
    __syncthreads();
#pragma unroll
    for (int kk = 0; kk < 2; ++kk) {
      frag8 a0 = *(const frag8*)&SX(w * 32 + l15, kk * 32 + quad * 8);
      frag8 a1 = *(const frag8*)&SX(w * 32 + 16 + l15, kk * 32 + quad * 8);
#pragma unroll
      for (int nt = 0; nt < 8; ++nt) {
        frag8 bf = *(const frag8*)&SW(nt * 16 + l15, kk * 32 + quad * 8);
        acc[0][nt] = __builtin_amdgcn_mfma_f32_16x16x32_bf16(a0, bf, acc[0][nt], 0, 0, 0);
        acc[1][nt] = __builtin_amdgcn_mfma_f32_16x16x32_bf16(a1, bf, acc[1][nt], 0, 0, 0);
      }
    }
    __syncthreads();
  }
#pragma unroll
  for (int mt = 0; mt < 2; ++mt)
#pragma unroll
    for (int nt = 0; nt < 8; ++nt)
#pragma unroll
      for (int r = 0; r < 4; ++r) {
        int m = w * 32 + mt * 16 + quad * 4 + r;
        int a = nt * 16 + l15;
        ST(a, m) = f2bf(acc[mt][nt][r]);
      }
  __syncthreads();
  {
    const uint4* sp = (const uint4*)&ST(row, half * 64);
    uint4* gp = (uint4*)(xWT + ((size_t)bb * AA + row) * TT + t0 + half * 64);
#pragma unroll
    for (int i = 0; i < 8; ++i) gp[i] = sp[i];
  }
#undef SX
#undef SW
#undef ST
}

// ---------- persistent step kernel (plain launch) ----------
// Blocks 0..511: attention, b = id>>4, 128-t chunk — the block's xWT slice
// (32 KB) and x slice (64 KB) are LOOP-INVARIANT and loaded ONCE into
// registers (pa[32] uints + pb[32] uint2s = 96 regs); per-step attention is
// pure VALU + LDS. Round-7 PMC: 613 MB HBM refetch of exactly this data at
// 460 GB/s == the whole 1372 us. Blocks 512..543: GRU, one per b.
// launch_bounds(256,3): 768 co-resident >= 544 -> spin-wait deadlock-free.
__global__ __launch_bounds__(256, 3) void step_coop(
    const ushortT* __restrict__ x_bf, const ushortT* __restrict__ xWT,
    const ushortT* __restrict__ Wih_bf, const ushortT* __restrict__ Whh_bf,
    const ushortT* __restrict__ Wh_bf, const float* __restrict__ v,
    const float* __restrict__ b_ih, const float* __restrict__ b_hh,
    float* ctx_acc, float* den, float* hwh_s, ushortT* hall_bf,
    int* ctxcnt, int* hcnt) {
  __shared__ float smem[2592];
  const int tid = threadIdx.x;
  const int id = blockIdx.x;
  if (id < 512) {
    // ================= attention role =================
    // smem: [0,128) hWh | [128,256) v | [256,1280) parts[8][128] |
    //       [1280,1408) w | [1536,2560) cpart[4][256]
    const int b = id >> 4, t0 = (id & 15) * 128;
    const int q = tid >> 5, tp = tid & 31;      // Phase A indices
    const int j4 = tid >> 6, dq = tid & 63;     // Phase B indices
    if (tid < 128) smem[128 + tid] = v[tid];
    // -------- one-time register staging (loop-invariant) --------
    uintT pa[32];   // xWT[a = q*16+i][t0 + c*64 + 2*tp], c in {0,1}
    {
      const ushortT* basep = xWT + (size_t)(b * AA + q * 16) * TT + t0 + 2 * tp;
#pragma unroll
      for (int c = 0; c < 2; ++c)
#pragma unroll
        for (int i = 0; i < 16; ++i)
          pa[c * 16 + i] = *(const uintT*)(basep + (size_t)i * TT + c * 64);
    }
    uint2 pb[32];   // x[t0 + j*4 + j4][4*dq .. 4*dq+4)
    {
      const uint2* xb = (const uint2*)(x_bf + ((size_t)b * TT + t0) * DD) + dq;
#pragma unroll
      for (int j = 0; j < 32; ++j)
        pb[j] = xb[(size_t)(j * 4 + j4) * 64];
    }
    for (int s = 0; s < NSTEPS; ++s) {
      if (s > 0) {
        if (tid == 0) wait_ge(&hcnt[s * 32 + b], 1);
        __syncthreads();
        __builtin_amdgcn_fence(__ATOMIC_ACQUIRE, "agent");
        if (tid < 128) smem[tid] = aload(&hwh_s[(size_t)(s * 32 + b) * 128 + tid]);
      } else {
        if (tid < 128) smem[tid] = 0.f;
      }
      __syncthreads();
      // Phase A: scores from registers
#pragma unroll
      for (int c = 0; c < 2; ++c) {
        float p0 = 0.f, p1 = 0.f;
#pragma unroll
        for (int i = 0; i < 16; ++i) {
          uintT u = pa[c * 16 + i];
          int a = q * 16 + i;
          float hwa = smem[a], va = smem[128 + a];
          p0 = fmaf(tanh_fast(bflo(u) + hwa), va, p0);
          p1 = fmaf(tanh_fast(bfhi(u) + hwa), va, p1);
        }
        smem[256 + q * 128 + c * 64 + 2 * tp] = p0;
        smem[256 + q * 128 + c * 64 + 2 * tp + 1] = p1;
      }
      __syncthreads();
      if (tid < 128) {
        float e = 0.f;
#pragma unroll
        for (int qq = 0; qq < 8; ++qq) e += smem[256 + qq * 128 + tid];
        smem[1280 + tid] = __expf(e);  // |e| <= ||v||_1 ~ 5: no overflow
      }
      __syncthreads();
      // Phase B: ctx partials from registers
      {
        float ax = 0.f, ay = 0.f, az = 0.f, aw = 0.f;
#pragma unroll
        for (int j = 0; j < 32; ++j) {
          float w = smem[1280 + j * 4 + j4];
          uint2 u = pb[j];
          ax = fmaf(w, bflo(u.x), ax); ay = fmaf(w, bfhi(u.x), ay);
          az = fmaf(w, bflo(u.y), az); aw = fmaf(w, bfhi(u.y), aw);
        }
        float4* pp = (float4*)&smem[1536 + j4 * 256 + dq * 4];
        *pp = make_float4(ax, ay, az, aw);
      }
      __syncthreads();
      {
        float sum = smem[1536 + tid] + smem[1792 + tid] + smem[2048 + tid] + smem[2304 + tid];
        atomicAdd(&ctx_acc[((size_t)s * 32 + b) * DD + tid], sum);
      }
      if (tid < 64) {
        float ds = smem[1280 + tid] + smem[1344 + tid];
#pragma unroll
        for (int off = 32; off > 0; off >>= 1) ds += __shfl_down(ds, off, 64);
        if (tid == 0) atomicAdd(&den[s * 32 + b], ds);
      }
      __syncthreads();  // drains vmcnt -> block's atomics globally visible
      if (tid == 0) {
        __builtin_amdgcn_fence(__ATOMIC_RELEASE, "agent");
        __hip_atomic_fetch_add(&ctxcnt[s * 32 + b], 1, __ATOMIC_RELAXED, __HIP_MEMORY_SCOPE_AGENT);
      }
    }
  } else {
    // ================= GRU role (one block per b) =================
    const int b = id - 512;
    smem[272 + tid + (tid >> 4)] = 0.f;  // h0 = 0 (stride-17 padded)
    for (int s = 1; s <= NSTEPS; ++s) {
      if (tid == 0) wait_ge(&ctxcnt[(s - 1) * 32 + b], 16);
      __syncthreads();
      __builtin_amdgcn_fence(__ATOMIC_ACQUIRE, "agent");
      float dv = aload(&den[(s - 1) * 32 + b]);
      float invd = 1.0f / dv;
      smem[tid + (tid >> 4)] =
          aload(&ctx_acc[((size_t)(s - 1) * 32 + b) * DD + tid]) * invd;
      __syncthreads();
      // gates: 16 lanes per gate, stride-17 LDS (conflict-free), bf16 weights
      {
        const int g16 = tid >> 4, l16 = tid & 15;
        const float* cp = &smem[l16 * 17];
        const float* hp = &smem[272 + l16 * 17];
        for (int p = 0; p < 48; ++p) {
          int g = p * 16 + g16;
          const uint4* wi = (const uint4*)(Wih_bf + (size_t)g * DD + l16 * 16);
          const uint4* wh = (const uint4*)(Whh_bf + (size_t)g * HH + l16 * 16);
          uint4 wa = wi[0], wb = wi[1], wc = wh[0], wd = wh[1];
          float gi = 0.f, gh = 0.f;
          dot8(cp, wa, gi); dot8(cp + 8, wb, gi);
          dot8(hp, wc, gh); dot8(hp + 8, wd, gh);
#pragma unroll
          for (int off = 8; off > 0; off >>= 1) {
            gi += __shfl_down(gi, off, 16);
            gh += __shfl_down(gh, off, 16);
          }
          if (l16 == 0) { smem[544 + g] = gi; smem[1312 + g] = gh; }
        }
      }
      __syncthreads();
      {
        int i = tid;
        float gir = smem[544 + i] + b_ih[i];
        float giz = smem[800 + i] + b_ih[256 + i];
        float gin = smem[1056 + i] + b_ih[512 + i];
        float ghr = smem[1312 + i] + b_hh[i];
        float ghz = smem[1568 + i] + b_hh[256 + i];
        float ghn = smem[1824 + i] + b_hh[512 + i];
        float r = sigmoid_fast(gir + ghr);
        float z = sigmoid_fast(giz + ghz);
        float n = tanh_fast(gin + r * ghn);
        float hv = (1.f - z) * n + z * smem[272 + i + (i >> 4)];
        smem[272 + i + (i >> 4)] = hv;  // own slot: read then write, no race
        hall_bf[((size_t)(s - 1) * 32 + b) * HH + i] = f2bf(hv);
      }
      __syncthreads();
      if (s < NSTEPS) {
        // hWh: thread (a-pair, k-quarter)
        const int a2 = tid & 63, kh = tid >> 6;
        float accx = 0.f, accy = 0.f;
#pragma unroll 8
        for (int k = kh * 64; k < kh * 64 + 64; ++k) {
          uintT u = *(const uintT*)(Wh_bf + (size_t)k * AA + a2 * 2);
          float hh = smem[272 + k + (k >> 4)];
          accx = fmaf(hh, bflo(u), accx);
          accy = fmaf(hh, bfhi(u), accy);
        }
        smem[2080 + kh * 128 + a2 * 2] = accx;
        smem[2080 + kh * 128 + a2 * 2 + 1] = accy;
        __syncthreads();
        if (tid < 128) {
          float hw = smem[2080 + tid] + smem[2208 + tid] + smem[2336 + tid] + smem[2464 + tid];
          __hip_atomic_store(&hwh_s[(size_t)(s * 32 + b) * 128 + tid], hw,
                             __ATOMIC_RELAXED, __HIP_MEMORY_SCOPE_AGENT);
        }
        __syncthreads();
        if (tid == 0) {
          __builtin_amdgcn_fence(__ATOMIC_RELEASE, "agent");
          __hip_atomic_fetch_add(&hcnt[s * 32 + b], 1, __ATOMIC_RELAXED,
                                 __HIP_MEMORY_SCOPE_AGENT);
        }
      }
    }
  }
}

// ---------- cls via MFMA bf16: [704 x 256] @ [256 x 4480] ----------
__global__ __launch_bounds__(256) void cls_mfma(
    const ushortT* __restrict__ hall_bf, const ushortT* __restrict__ Wcls_bf,
    const float* __restrict__ b_cls, float* __restrict__ out) {
  __shared__ ushortT sA[64 * 264];
  const int tid = threadIdx.x;
  const int n0 = blockIdx.x * 128, m0 = blockIdx.y * 64;
  {
    const int r = tid >> 2, seg = tid & 3;
    const uint4* src = (const uint4*)hall_bf;
    uint4* dstrow = (uint4*)(sA + r * 264);
#pragma unroll
    for (int j = 0; j < 8; ++j)
      dstrow[seg * 8 + j] = src[(size_t)(m0 + r) * 32 + seg * 8 + j];
  }
  __syncthreads();
  const int lane = tid & 63, w = tid >> 6;
  const int l15 = lane & 15, quad = lane >> 4;
  f32x4 acc[8];
#pragma unroll
  for (int nt = 0; nt < 8; ++nt) acc[nt] = (f32x4){0.f, 0.f, 0.f, 0.f};
#pragma unroll
  for (int kk = 0; kk < 8; ++kk) {
    frag8 af = *(const frag8*)(sA + (w * 16 + l15) * 264 + kk * 32 + quad * 8);
#pragma unroll
    for (int nt = 0; nt < 8; ++nt) {
      frag8 bf = *(const frag8*)(Wcls_bf + (size_t)(n0 + nt * 16 + l15) * 256 + kk * 32 + quad * 8);
      acc[nt] = __builtin_amdgcn_mfma_f32_16x16x32_bf16(af, bf, acc[nt], 0, 0, 0);
    }
  }
#pragma unroll
  for (int nt = 0; nt < 8; ++nt) {
    int n = n0 + nt * 16 + l15;
    if (n < CC) {
      float bc = b_cls[n];
#pragma unroll
      for (int r = 0; r < 4; ++r) {
        int m = m0 + w * 16 + quad * 4 + r;  // m = s*32 + b
        int st = m >> 5, bb = m & 31;
        out[((size_t)bb * NSTEPS + st) * CC + n] = acc[nt][r] + bc;
      }
    }
  }
}

extern "C" void kernel_launch(void* const* d_in, const int* in_sizes, int n_in,
                              void* d_out, int out_size, void* d_ws, size_t ws_size,
                              hipStream_t stream) {
  const float* x     = (const float*)d_in[0];
  const float* Wx    = (const float*)d_in[1];
  const float* Wh    = (const float*)d_in[2];
  const float* v     = (const float*)d_in[3];
  const float* W_ih  = (const float*)d_in[4];
  const float* W_hh  = (const float*)d_in[5];
  const float* b_ih  = (const float*)d_in[6];
  const float* b_hh  = (const float*)d_in[7];
  const float* W_cls = (const float*)d_in[8];
  const float* b_cls = (const float*)d_in[9];
  float* out = (float*)d_out;

  // workspace layout (~52.5 MiB)
  float* ctx_acc = (float*)d_ws;                       // 22*32*256 = 180224
  float* den     = ctx_acc + (size_t)NSTEPS * BB * DD; // 704
  int*   ctxcnt  = (int*)(den + NSTEPS * BB);          // 704
  int*   hcnt    = ctxcnt + NSTEPS * BB;               // 736
  float* hwh_s   = (float*)(hcnt + 736);               // 23*32*128 = 94208
  ushortT* hall_bf = (ushortT*)(hwh_s + 94208);        // 704*256 = 180224
  ushortT* Wih_bf  = hall_bf + 180224;                 // 768*256
  ushortT* Whh_bf  = Wih_bf + 196608;                  // 768*256
  ushortT* Wh_bf   = Whh_bf + 196608;                  // 256*128
  ushortT* Wcls_bf = Wh_bf + 32768;                    // 4480*256
  ushortT* WxT_bf  = Wcls_bf + 1146880;                // 128*256
  ushortT* x_bf    = WxT_bf + 32768;                   // 65536*256
  ushortT* xWT     = x_bf + (size_t)BB * TT * DD;      // 32*128*2048

  hipMemsetAsync(ctx_acc, 0,
                 (size_t)(NSTEPS * BB * DD + NSTEPS * BB + NSTEPS * BB + 736) * sizeof(float),
                 stream);
  conv_kernel<<<416, 256, 0, stream>>>(Wx, W_cls, W_ih, W_hh, Wh,
                                       Wcls_bf, Wih_bf, Whh_bf, Wh_bf, WxT_bf);
  xw_mfma<<<(BB * TT) / 128, 256, 0, stream>>>(x, WxT_bf, x_bf, xWT);

  step_coop<<<544, 256, 0, stream>>>(x_bf, xWT, Wih_bf, Whh_bf, Wh_bf, v,
                                     b_ih, b_hh, ctx_acc, den, hwh_s, hall_bf,
                                     ctxcnt, hcnt);

  cls_mfma<<<dim3(35, 11), 256, 0, stream>>>(hall_bf, Wcls_bf, b_cls, out);
}

// Round 9
// 1179.750 us; speedup vs baseline: 1.3613x; 1.3613x over previous
//
#include <hip/hip_runtime.h>
#include <hip/hip_fp8.h>

#define BB 32
#define TT 2048
#define DD 256
#define HH 256
#define AA 128
#define CC 4367
#define NSTEPS 22

typedef unsigned short ushortT;
typedef unsigned int uintT;
using frag8 = __attribute__((ext_vector_type(8))) short;
using f32x4 = __attribute__((ext_vector_type(4))) float;
using f32x2 = __attribute__((ext_vector_type(2))) float;

__device__ __forceinline__ float tanh_fast(float u) {
  float e = __expf(2.0f * u);
  return 1.0f - 2.0f / (e + 1.0f);
}
__device__ __forceinline__ float sigmoid_fast(float u) {
  return 1.0f / (1.0f + __expf(-u));
}
__device__ __forceinline__ ushortT f2bf(float f) {
  unsigned int u = __float_as_uint(f);
  unsigned int r = (u + 0x7FFFu + ((u >> 16) & 1u)) >> 16;
  return (ushortT)r;
}
__device__ __forceinline__ float bflo(uintT u) { return __uint_as_float(u << 16); }
__device__ __forceinline__ float bfhi(uintT u) { return __uint_as_float(u & 0xffff0000u); }

__device__ __forceinline__ void wait_ge(int* p, int tgt) {
  while (__hip_atomic_load(p, __ATOMIC_RELAXED, __HIP_MEMORY_SCOPE_AGENT) < tgt)
    __builtin_amdgcn_s_sleep(2);
}
__device__ __forceinline__ float aload(const float* p) {
  return __hip_atomic_load(p, __ATOMIC_RELAXED, __HIP_MEMORY_SCOPE_AGENT);
}
__device__ __forceinline__ void astore(float* p, float v) {
  __hip_atomic_store(p, v, __ATOMIC_RELAXED, __HIP_MEMORY_SCOPE_AGENT);
}
__device__ __forceinline__ void dot8(const float* cp, uint4 w, float& acc) {
  acc = fmaf(cp[0], bflo(w.x), acc); acc = fmaf(cp[1], bfhi(w.x), acc);
  acc = fmaf(cp[2], bflo(w.y), acc); acc = fmaf(cp[3], bfhi(w.y), acc);
  acc = fmaf(cp[4], bflo(w.z), acc); acc = fmaf(cp[5], bfhi(w.z), acc);
  acc = fmaf(cp[6], bflo(w.w), acc); acc = fmaf(cp[7], bfhi(w.w), acc);
}

// fp8 e4m3 (OCP) pack/unpack — hw cvt when available, hip_fp8 class fallback
__device__ __forceinline__ uintT f32x4_to_fp8(float a, float b, float c, float d) {
#if __has_builtin(__builtin_amdgcn_cvt_pk_fp8_f32)
  int r = __builtin_amdgcn_cvt_pk_fp8_f32(a, b, 0, false);
  r = __builtin_amdgcn_cvt_pk_fp8_f32(c, d, r, true);
  return (uintT)r;
#else
  __hip_fp8_e4m3 qa(a), qb(b), qc(c), qd(d);
  return (uintT)qa.__x | ((uintT)qb.__x << 8) | ((uintT)qc.__x << 16) | ((uintT)qd.__x << 24);
#endif
}
__device__ __forceinline__ void fp8x4_to_f32(uintT u, float* o) {
#if __has_builtin(__builtin_amdgcn_cvt_pk_f32_fp8)
  f32x2 lo = __builtin_amdgcn_cvt_pk_f32_fp8((int)u, false);
  f32x2 hi = __builtin_amdgcn_cvt_pk_f32_fp8((int)u, true);
  o[0] = lo[0]; o[1] = lo[1]; o[2] = hi[0]; o[3] = hi[1];
#else
  __hip_fp8_e4m3 t0, t1, t2, t3;
  t0.__x = (u) & 0xff; t1.__x = (u >> 8) & 0xff;
  t2.__x = (u >> 16) & 0xff; t3.__x = (u >> 24) & 0xff;
  o[0] = (float)t0; o[1] = (float)t1; o[2] = (float)t2; o[3] = (float)t3;
#endif
}

// ---------- prep: bf16 conversions + WxT transpose ----------
__global__ __launch_bounds__(256) void conv_kernel(
    const float* __restrict__ Wx, const float* __restrict__ W_cls,
    const float* __restrict__ W_ih, const float* __restrict__ W_hh,
    const float* __restrict__ Wh,
    ushortT* __restrict__ Wcls_bf, ushortT* __restrict__ Wih_bf,
    ushortT* __restrict__ Whh_bf, ushortT* __restrict__ Wh_bf,
    ushortT* __restrict__ WxT_bf) {
  int blk = blockIdx.x;
  const int tid = threadIdx.x;
  if (blk < 384) {
    const float* src; ushortT* dst; int base, srcn;
    if (blk < 280)      { src = W_cls; dst = Wcls_bf; base = blk * 4096;        srcn = CC * 256; }
    else if (blk < 328) { src = W_ih;  dst = Wih_bf;  base = (blk - 280) * 4096; srcn = 768 * 256; }
    else if (blk < 376) { src = W_hh;  dst = Whh_bf;  base = (blk - 328) * 4096; srcn = 768 * 256; }
    else                { src = Wh;    dst = Wh_bf;   base = (blk - 376) * 4096; srcn = 256 * 128; }
#pragma unroll
    for (int i = 0; i < 16; ++i) {
      int idx = base + i * 256 + tid;
      dst[idx] = (idx < srcn) ? f2bf(src[idx]) : (ushortT)0;
    }
  } else {  // Wx [256][128] -> WxT_bf [128][256]
    blk -= 384;
    __shared__ float tile[32][33];
    const int li = tid >> 5, lj = tid & 31;
    int i0 = (blk >> 2) * 32, j0 = (blk & 3) * 32;
#pragma unroll
    for (int k = 0; k < 4; ++k)
      tile[li + k * 8][lj] = Wx[(size_t)(i0 + li + k * 8) * 128 + j0 + lj];
    __syncthreads();
#pragma unroll
    for (int k = 0; k < 4; ++k) {
      int j = j0 + li + k * 8;
      WxT_bf[(size_t)j * 256 + i0 + lj] = f2bf(tile[lj][li + k * 8]);
    }
  }
}

// ---------- xW via MFMA bf16 (validated): emits x_fp8 and xWT ----------
__global__ __launch_bounds__(256) void xw_mfma(
    const float* __restrict__ x, const ushortT* __restrict__ WxT_bf,
    unsigned char* __restrict__ x_fp8, ushortT* __restrict__ xWT) {
  __shared__ ushortT lds[2 * 128 * 72];
#define SX(r, c) lds[(r) * 72 + (c)]
#define SW(r, c) lds[128 * 72 + (r) * 72 + (c)]
#define ST(a, m) lds[(a) * 136 + (m)]
  const int tid = threadIdx.x;
  const int lane = tid & 63, w = tid >> 6;
  const int l15 = lane & 15, quad = lane >> 4;
  const int r0 = blockIdx.x * 128;
  const int bb = blockIdx.x >> 4, t0 = (blockIdx.x & 15) * 128;
  const int row = tid >> 1, half = tid & 1;

  f32x4 acc[2][8];
#pragma unroll
  for (int mt = 0; mt < 2; ++mt)
#pragma unroll
    for (int nt = 0; nt < 8; ++nt) acc[mt][nt] = (f32x4){0.f, 0.f, 0.f, 0.f};

  for (int kk0 = 0; kk0 < 256; kk0 += 64) {
    {
      const float4* xp = (const float4*)(x + (size_t)(r0 + row) * DD + kk0 + half * 32);
      uint2* fq = (uint2*)(x_fp8 + (size_t)(r0 + row) * DD + kk0 + half * 32);
      uint4* sxp = (uint4*)&SX(row, half * 32);
#pragma unroll
      for (int i = 0; i < 4; ++i) {
        float4 f0 = xp[2 * i], f1 = xp[2 * i + 1];
        uint4 pk;
        pk.x = (uintT)f2bf(f0.x) | ((uintT)f2bf(f0.y) << 16);
        pk.y = (uintT)f2bf(f0.z) | ((uintT)f2bf(f0.w) << 16);
        pk.z = (uintT)f2bf(f1.x) | ((uintT)f2bf(f1.y) << 16);
        pk.w = (uintT)f2bf(f1.z) | ((uintT)f2bf(f1.w) << 16);
        sxp[i] = pk;
        uint2 q;
        q.x = f32x4_to_fp8(f0.x, f0.y, f0.z, f0.w);
        q.y = f32x4_to_fp8(f1.x, f1.y, f1.z, f1.w);
        fq[i] = q;
      }
    }
    {
      const uint4* wp = (const uint4*)(WxT_bf + (size_t)row * DD + kk0 + half * 32);
      uint4* swp = (uint4*)&SW(row, half * 32);
#pragma unroll
      for (int i = 0; i < 4; ++i) swp[i] = wp[i];
    }
    __syncthreads();
#pragma unroll
    for (int kk = 0; kk < 2; ++kk) {
      frag8 a0 = *(const frag8*)&SX(w * 32 + l15, kk * 32 + quad * 8);
      frag8 a1 = *(const frag8*)&SX(w * 32 + 16 + l15, kk * 32 + quad * 8);
#pragma unroll
      for (int nt = 0; nt < 8; ++nt) {
        frag8 bf = *(const frag8*)&SW(nt * 16 + l15, kk * 32 + quad * 8);
        acc[0][nt] = __builtin_amdgcn_mfma_f32_16x16x32_bf16(a0, bf, acc[0][nt], 0, 0, 0);
        acc[1][nt] = __builtin_amdgcn_mfma_f32_16x16x32_bf16(a1, bf, acc[1][nt], 0, 0, 0);
      }
    }
    __syncthreads();
  }
#pragma unroll
  for (int mt = 0; mt < 2; ++mt)
#pragma unroll
    for (int nt = 0; nt < 8; ++nt)
#pragma unroll
      for (int r = 0; r < 4; ++r) {
        int m = w * 32 + mt * 16 + quad * 4 + r;
        int a = nt * 16 + l15;
        ST(a, m) = f2bf(acc[mt][nt][r]);
      }
  __syncthreads();
  {
    const uint4* sp = (const uint4*)&ST(row, half * 64);
    uint4* gp = (uint4*)(xWT + ((size_t)bb * AA + row) * TT + t0 + half * 64);
#pragma unroll
    for (int i = 0; i < 8; ++i) gp[i] = sp[i];
  }
#undef SX
#undef SW
#undef ST
}

// ---------- persistent LDS-resident step kernel ----------
// 256 blocks (b = id>>3, chunk c = id&7 over 256 t's), one per CU (LDS ~140 KB
// forces 1 block/CU -> all 256 co-resident; spin-waits deadlock-free for ANY
// VGPR count — the round-8 spill showed register arrays are compiler-fragile).
// Per block, staged ONCE into LDS: xWT slice bf16 (64 KB) + x slice fp8 (64 KB).
// GRU is DISTRIBUTED: each block computes its 96-gate slice (L2-resident
// weights, 98 KB/step/block) and publishes its 32 h values fp32.
// smem float layout: [0,128) hWh | [128,256) v | 256 parts(1024)/G_SC(288) |
// 1280 w(256) | 1536 cpart(1024)/G_HP(512) | 2560 den(4) | 2568 gi(96) |
// 2664 gh(96) | 2760 h stride-17 (272)
#define P_HWH 0
#define P_V 128
#define P_PARTS 256
#define G_SC 256
#define P_W 1280
#define P_CP 1536
#define G_HP 1536
#define P_DEN 2560
#define G_GI 2568
#define G_GH 2664
#define P_H 2760
__global__ __launch_bounds__(256) void step_coop(
    const unsigned char* __restrict__ x_fp8, const ushortT* __restrict__ xWT,
    const ushortT* __restrict__ Wih_bf, const ushortT* __restrict__ Whh_bf,
    const ushortT* __restrict__ Wh_bf, const float* __restrict__ v,
    const float* __restrict__ b_ih, const float* __restrict__ b_hh,
    float* ctx_acc, float* den, float* hflt, ushortT* hall_bf,
    int* ctxcnt, int* hcnt) {
  __shared__ __align__(16) ushortT s_xwt[AA * 256];        // 64 KB  [a][t]
  __shared__ __align__(16) unsigned char s_xq[256 * 256];  // 64 KB  [t][d]
  __shared__ float smem[3040];
  const int tid = threadIdx.x;
  const int b = blockIdx.x >> 3, c = blockIdx.x & 7;
  const int t0 = c * 256, i0 = c * 32;
  const int q = tid >> 6, tp = tid & 63;   // Phase A
  const int j4 = tid >> 6, dq = tid & 63;  // Phase B / hWh

  // ---- one-time staging ----
  if (tid < 128) { smem[P_HWH + tid] = 0.f; smem[P_V + tid] = v[tid]; }
  smem[P_H + tid + (tid >> 4)] = 0.f;
  {
    uint4* dst = (uint4*)s_xwt;
#pragma unroll
    for (int k = 0; k < 16; ++k) {
      int idx = k * 256 + tid;
      int a = idx >> 5, u = idx & 31;
      dst[idx] = *(const uint4*)(xWT + ((size_t)(b * AA + a)) * TT + t0 + u * 8);
    }
    uint4* dq8 = (uint4*)s_xq;
#pragma unroll
    for (int k = 0; k < 16; ++k) {
      int idx = k * 256 + tid;
      int t = idx >> 4, u = idx & 15;
      dq8[idx] = *(const uint4*)(x_fp8 + ((size_t)(b * TT + t0 + t)) * DD + u * 16);
    }
  }
  __syncthreads();

  const uintT* xwt32 = (const uintT*)s_xwt;  // [a][tpair] 128x128
  const uintT* xq32 = (const uintT*)s_xq;    // [t][d4]    256x64

  for (int s = 0; s < NSTEPS; ++s) {
    // ---- Phase A: scores (wave q covers a in [32q,32q+32)) ----
#pragma unroll
    for (int th = 0; th < 2; ++th) {
      float p0 = 0.f, p1 = 0.f;
#pragma unroll 8
      for (int i = 0; i < 32; ++i) {
        int a = q * 32 + i;
        uintT u = xwt32[a * 128 + th * 64 + tp];
        float hwa = smem[P_HWH + a], va = smem[P_V + a];
        p0 = fmaf(tanh_fast(bflo(u) + hwa), va, p0);
        p1 = fmaf(tanh_fast(bfhi(u) + hwa), va, p1);
      }
      int t = th * 128 + 2 * tp;
      smem[P_PARTS + q * 256 + t] = p0;
      smem[P_PARTS + q * 256 + t + 1] = p1;
    }
    __syncthreads();
    {
      float e = smem[P_PARTS + tid] + smem[P_PARTS + 256 + tid] +
                smem[P_PARTS + 512 + tid] + smem[P_PARTS + 768 + tid];
      float wv = __expf(e);  // |e| <= ||v||_1 ~ 5: no overflow
      smem[P_W + tid] = wv;
      float ds = wv;
#pragma unroll
      for (int off = 32; off > 0; off >>= 1) ds += __shfl_down(ds, off, 64);
      if ((tid & 63) == 0) smem[P_DEN + (tid >> 6)] = ds;
    }
    __syncthreads();
    // ---- Phase B: ctx partials from LDS fp8 x ----
    {
      float ax = 0.f, ay = 0.f, az = 0.f, aw = 0.f;
#pragma unroll 8
      for (int j = 0; j < 64; ++j) {
        int t = j * 4 + j4;
        float w = smem[P_W + t];
        uintT u = xq32[t * 64 + dq];
        float o[4];
        fp8x4_to_f32(u, o);
        ax = fmaf(w, o[0], ax); ay = fmaf(w, o[1], ay);
        az = fmaf(w, o[2], az); aw = fmaf(w, o[3], aw);
      }
      float4* pp = (float4*)&smem[P_CP + j4 * 256 + dq * 4];
      *pp = make_float4(ax, ay, az, aw);
    }
    __syncthreads();
    {
      float sum = smem[P_CP + tid] + smem[P_CP + 256 + tid] +
                  smem[P_CP + 512 + tid] + smem[P_CP + 768 + tid];
      atomicAdd(&ctx_acc[((size_t)s * 32 + b) * DD + tid], sum);
      if (tid == 0) {
        float dsum = smem[P_DEN] + smem[P_DEN + 1] + smem[P_DEN + 2] + smem[P_DEN + 3];
        atomicAdd(&den[s * 32 + b], dsum);
      }
    }
    __syncthreads();  // drains vmcnt -> atomics globally visible
    if (tid == 0) {
      __builtin_amdgcn_fence(__ATOMIC_RELEASE, "agent");
      __hip_atomic_fetch_add(&ctxcnt[s * 32 + b], 1, __ATOMIC_RELAXED, __HIP_MEMORY_SCOPE_AGENT);
    }
    // ---- distributed GRU: this block computes gates/h for i in [i0,i0+32) ----
    if (tid == 0) wait_ge(&ctxcnt[s * 32 + b], 8);
    __syncthreads();
    __builtin_amdgcn_fence(__ATOMIC_ACQUIRE, "agent");
    {
      float dv = aload(&den[s * 32 + b]);
      float invd = 1.0f / dv;
      smem[G_SC + tid + (tid >> 4)] = aload(&ctx_acc[((size_t)s * 32 + b) * DD + tid]) * invd;
    }
    __syncthreads();
    {
      const int g16 = tid >> 4, l16 = tid & 15;
      const float* cp = &smem[G_SC + l16 * 17];
      const float* hp = &smem[P_H + l16 * 17];
#pragma unroll
      for (int p = 0; p < 6; ++p) {
        int gl = p * 16 + g16;                 // 0..95
        int seg = gl >> 5, off = gl & 31;
        int grow = seg * 256 + i0 + off;
        const uint4* wi = (const uint4*)(Wih_bf + (size_t)grow * DD + l16 * 16);
        const uint4* wh = (const uint4*)(Whh_bf + (size_t)grow * HH + l16 * 16);
        uint4 wa = wi[0], wb = wi[1], wc = wh[0], wd = wh[1];
        float gi = 0.f, gh = 0.f;
        dot8(cp, wa, gi); dot8(cp + 8, wb, gi);
        dot8(hp, wc, gh); dot8(hp + 8, wd, gh);
#pragma unroll
        for (int off2 = 8; off2 > 0; off2 >>= 1) {
          gi += __shfl_down(gi, off2, 16);
          gh += __shfl_down(gh, off2, 16);
        }
        if (l16 == 0) {
          smem[G_GI + gl] = gi + b_ih[grow];
          smem[G_GH + gl] = gh + b_hh[grow];
        }
      }
    }
    __syncthreads();
    if (tid < 32) {
      int i = i0 + tid;
      float r = sigmoid_fast(smem[G_GI + tid] + smem[G_GH + tid]);
      float z = sigmoid_fast(smem[G_GI + 32 + tid] + smem[G_GH + 32 + tid]);
      float n = tanh_fast(smem[G_GI + 64 + tid] + r * smem[G_GH + 64 + tid]);
      float hp = smem[P_H + i + (i >> 4)];
      float hv = (1.f - z) * n + z * hp;
      hall_bf[((size_t)s * 32 + b) * HH + i] = f2bf(hv);
      astore(&hflt[((size_t)s * 32 + b) * HH + i], hv);
    }
    __syncthreads();  // drain h publishes
    if (s + 1 < NSTEPS) {
      if (tid == 0) {
        __builtin_amdgcn_fence(__ATOMIC_RELEASE, "agent");
        __hip_atomic_fetch_add(&hcnt[s * 32 + b], 1, __ATOMIC_RELAXED, __HIP_MEMORY_SCOPE_AGENT);
        wait_ge(&hcnt[s * 32 + b], 8);
      }
      __syncthreads();
      __builtin_amdgcn_fence(__ATOMIC_ACQUIRE, "agent");
      {
        float hv = aload(&hflt[((size_t)s * 32 + b) * HH + tid]);
        smem[P_H + tid + (tid >> 4)] = hv;
      }
      __syncthreads();
      // hWh (redundant per block, trivial): wave kh covers k-quarter
      {
        const int a2 = dq, kh = j4;
        float accx = 0.f, accy = 0.f;
#pragma unroll 8
        for (int k = kh * 64; k < kh * 64 + 64; ++k) {
          uintT u = *(const uintT*)(Wh_bf + (size_t)k * AA + a2 * 2);
          float hh = smem[P_H + k + (k >> 4)];
          accx = fmaf(hh, bflo(u), accx);
          accy = fmaf(hh, bfhi(u), accy);
        }
        smem[G_HP + kh * 128 + a2 * 2] = accx;
        smem[G_HP + kh * 128 + a2 * 2 + 1] = accy;
      }
      __syncthreads();
      if (tid < 128)
        smem[P_HWH + tid] = smem[G_HP + tid] + smem[G_HP + 128 + tid] +
                            smem[G_HP + 256 + tid] + smem[G_HP + 384 + tid];
      __syncthreads();
    }
  }
}

// ---------- cls via MFMA bf16: [704 x 256] @ [256 x 4480] ----------
__global__ __launch_bounds__(256) void cls_mfma(
    const ushortT* __restrict__ hall_bf, const ushortT* __restrict__ Wcls_bf,
    const float* __restrict__ b_cls, float* __restrict__ out) {
  __shared__ ushortT sA[64 * 264];
  const int tid = threadIdx.x;
  const int n0 = blockIdx.x * 128, m0 = blockIdx.y * 64;
  {
    const int r = tid >> 2, seg = tid & 3;
    const uint4* src = (const uint4*)hall_bf;
    uint4* dstrow = (uint4*)(sA + r * 264);
#pragma unroll
    for (int j = 0; j < 8; ++j)
      dstrow[seg * 8 + j] = src[(size_t)(m0 + r) * 32 + seg * 8 + j];
  }
  __syncthreads();
  const int lane = tid & 63, w = tid >> 6;
  const int l15 = lane & 15, quad = lane >> 4;
  f32x4 acc[8];
#pragma unroll
  for (int nt = 0; nt < 8; ++nt) acc[nt] = (f32x4){0.f, 0.f, 0.f, 0.f};
#pragma unroll
  for (int kk = 0; kk < 8; ++kk) {
    frag8 af = *(const frag8*)(sA + (w * 16 + l15) * 264 + kk * 32 + quad * 8);
#pragma unroll
    for (int nt = 0; nt < 8; ++nt) {
      frag8 bf = *(const frag8*)(Wcls_bf + (size_t)(n0 + nt * 16 + l15) * 256 + kk * 32 + quad * 8);
      acc[nt] = __builtin_amdgcn_mfma_f32_16x16x32_bf16(af, bf, acc[nt], 0, 0, 0);
    }
  }
#pragma unroll
  for (int nt = 0; nt < 8; ++nt) {
    int n = n0 + nt * 16 + l15;
    if (n < CC) {
      float bc = b_cls[n];
#pragma unroll
      for (int r = 0; r < 4; ++r) {
        int m = m0 + w * 16 + quad * 4 + r;  // m = s*32 + b
        int st = m >> 5, bb = m & 31;
        out[((size_t)bb * NSTEPS + st) * CC + n] = acc[nt][r] + bc;
      }
    }
  }
}

extern "C" void kernel_launch(void* const* d_in, const int* in_sizes, int n_in,
                              void* d_out, int out_size, void* d_ws, size_t ws_size,
                              hipStream_t stream) {
  const float* x     = (const float*)d_in[0];
  const float* Wx    = (const float*)d_in[1];
  const float* Wh    = (const float*)d_in[2];
  const float* v     = (const float*)d_in[3];
  const float* W_ih  = (const float*)d_in[4];
  const float* W_hh  = (const float*)d_in[5];
  const float* b_ih  = (const float*)d_in[6];
  const float* b_hh  = (const float*)d_in[7];
  const float* W_cls = (const float*)d_in[8];
  const float* b_cls = (const float*)d_in[9];
  float* out = (float*)d_out;

  // workspace (~37 MiB)
  float* ctx_acc = (float*)d_ws;                       // 22*32*256 = 180224
  float* den     = ctx_acc + (size_t)NSTEPS * BB * DD; // 704
  int*   ctxcnt  = (int*)(den + NSTEPS * BB);          // 704
  int*   hcnt    = ctxcnt + NSTEPS * BB;               // 704
  float* hflt    = (float*)(hcnt + NSTEPS * BB);       // 22*32*256 = 180224
  ushortT* hall_bf = (ushortT*)(hflt + (size_t)NSTEPS * BB * HH);  // 180224
  ushortT* Wih_bf  = hall_bf + 180224;                 // 768*256
  ushortT* Whh_bf  = Wih_bf + 196608;                  // 768*256
  ushortT* Wh_bf   = Whh_bf + 196608;                  // 256*128
  ushortT* Wcls_bf = Wh_bf + 32768;                    // 4480*256
  ushortT* WxT_bf  = Wcls_bf + 1146880;                // 128*256
  unsigned char* x_fp8 = (unsigned char*)(WxT_bf + 32768);  // 32*2048*256 B
  ushortT* xWT = (ushortT*)(x_fp8 + (size_t)BB * TT * DD);  // 32*128*2048

  hipMemsetAsync(ctx_acc, 0,
                 (size_t)(NSTEPS * BB * DD + 3 * NSTEPS * BB) * sizeof(float), stream);
  conv_kernel<<<416, 256, 0, stream>>>(Wx, W_cls, W_ih, W_hh, Wh,
                                       Wcls_bf, Wih_bf, Whh_bf, Wh_bf, WxT_bf);
  xw_mfma<<<(BB * TT) / 128, 256, 0, stream>>>(x, WxT_bf, x_fp8, xWT);

  step_coop<<<256, 256, 0, stream>>>(x_fp8, xWT, Wih_bf, Whh_bf, Wh_bf, v,
                                     b_ih, b_hh, ctx_acc, den, hflt, hall_bf,
                                     ctxcnt, hcnt);

  cls_mfma<<<dim3(35, 11), 256, 0, stream>>>(hall_bf, Wcls_bf, b_cls, out);
}